// Round 3
// baseline (1292.246 us; speedup 1.0000x reference)
//
#include <hip/hip_runtime.h>

#define NV   20000
#define NNB  12
#define NC   16
#define NH   4
#define VPB  8

// ws layout: int flag at offset 0; A[24576] floats at offset 64 floats.

// ---------------------------------------------------------------------------
// Mask dtype detection: if mask is stored as int32 (values 0/1), every byte
// at offset % 4 != 0 is zero. If stored as 1-byte bool (~80% ones), nonzero
// bytes appear at those offsets with certainty. flag=1 -> byte storage.
// ---------------------------------------------------------------------------
__global__ __launch_bounds__(256) void kdetect(const unsigned char* __restrict__ m,
                                               int* __restrict__ flag)
{
    __shared__ int s_nz;
    if (threadIdx.x == 0) s_nz = 0;
    __syncthreads();
    int nz = 0;
    for (int k = blockIdx.x * 256 + threadIdx.x; k < NV * NNB; k += gridDim.x * 256) {
        if ((k & 3) != 0 && m[k] != 0) nz = 1;
    }
    if (nz) atomicOr(&s_nz, 1);
    __syncthreads();
    if (threadIdx.x == 0 && s_nz) atomicOr(flag, 1);   // 1 => byte storage
}

// ---------------------------------------------------------------------------
// A[h][c][i][j][p], p in {1, u0, u1, u0^2, 2u0u1, u1^2}; flat = k*48+j*6+p,
// k = (h*16+c)*8+i.
// ---------------------------------------------------------------------------
__global__ __launch_bounds__(256) void ksetup(
    const float* __restrict__ v0p, const float* __restrict__ v1p,
    const float* __restrict__ v2p, const float* __restrict__ vb1,
    const float* __restrict__ vb2, float* __restrict__ A)
{
    int idx = blockIdx.x * 256 + threadIdx.x;
    if (idx >= 24576) return;
    int p = idx % 6;
    int t = idx / 6;
    int j = t & 7;  t >>= 3;
    int i = t & 7;  t >>= 3;
    int c = t & 15; t >>= 4;
    int h = t;
    float s = 0.f;
    if (p == 0) {
        s = v0p[h*128 + c*8 + ((j - i + 8) & 7)];
    } else if (p <= 2) {
        int o = p - 1;
        #pragma unroll
        for (int b = 0; b < 8; ++b)
            s += v1p[h*128 + c*8 + b] * vb1[((b*2 + o)*8 + i)*8 + j];
    } else {
        int o = p - 3;
        #pragma unroll
        for (int b = 0; b < 8; ++b)
            s += v2p[h*128 + c*8 + b] * vb2[((b*3 + o)*8 + i)*8 + j];
    }
    A[idx] = s;
}

// ---------------------------------------------------------------------------
// Fused main: VPB vertices per block, A/wm slices held in registers.
// ---------------------------------------------------------------------------
__global__ __launch_bounds__(256) void kmain(
    const float* __restrict__ x, const int* __restrict__ nbr,
    const unsigned char* __restrict__ mskb, const float* __restrict__ pt,
    const float* __restrict__ rel, const float* __restrict__ qc,
    const float* __restrict__ kc, const float* __restrict__ A,
    const float* __restrict__ wm, const int* __restrict__ flagp,
    float* __restrict__ out)
{
    const int tid = threadIdx.x;
    const int vbase = blockIdx.x * VPB;
    const int bytemode = flagp[0];           // 1 => bool bytes, 0 => int32
    const int* mski = (const int*)mskb;

    __shared__ __align__(16) float smem[8920];
    __shared__ __align__(16) float s_head[576];      // [cp][j] stride 9
    float* s_x    = smem;          // 128
    float* s_xn   = smem + 128;    // 1536
    float* s_pt   = smem + 1664;   // 768
    float* s_f    = smem + 2432;   // 1536   [n][c][i]
    float* s_qc   = smem + 3968;   // 512
    float* s_kc   = smem + 4480;   // 512
    float* s_Q    = smem + 4992;   // 32
    float* s_K    = smem + 5024;   // 384    [n][h][i]
    float* s_sc   = smem + 5408;   // 48     [n][h]
    float* s_den  = smem + 5456;   // 4
    float* s_nv   = smem + 5460;   // 1 (pad to 5464)
    float* s_scal = smem + 5464;   // 72     [n][p]
    float* s_w    = smem + 5536;   // 288    [n][h*6+p]
    float* s_G    = smem + 5824;   // 3072   [h][p][c][j]  (aliased by s_part)
    int*   s_nb   = (int*)(smem + 8896); // 12
    float* s_m    = smem + 8908;   // 12

    // --- persistent register tiles -----------------------------------------
    float a0[48], a1[48];
    {
        const float4* p0 = (const float4*)(A + tid*48);
        const float4* p1 = (const float4*)(A + (tid+256)*48);
        #pragma unroll
        for (int q = 0; q < 12; ++q) {
            float4 t0 = p0[q], t1 = p1[q];
            a0[q*4+0]=t0.x; a0[q*4+1]=t0.y; a0[q*4+2]=t0.z; a0[q*4+3]=t0.w;
            a1[q*4+0]=t1.x; a1[q*4+1]=t1.y; a1[q*4+2]=t1.z; a1[q*4+3]=t1.w;
        }
    }
    float wreg[32];
    {
        const int o = tid >> 4, g4 = tid & 15;
        const float4* wp = (const float4*)(wm + o*512 + g4*32);
        #pragma unroll
        for (int q = 0; q < 8; ++q) {
            float4 w = wp[q];
            wreg[q*4+0]=w.x; wreg[q*4+1]=w.y; wreg[q*4+2]=w.z; wreg[q*4+3]=w.w;
        }
    }
    for (int k = tid; k < 512; k += 256) { s_qc[k] = qc[k]; s_kc[k] = kc[k]; }

    for (int vi = 0; vi < VPB; ++vi) {
        const int v = vbase + vi;

        // --- stage inputs ---------------------------------------------------
        if (tid < 128) s_x[tid] = x[v*128 + tid];
        if (tid >= 128 && tid < 128 + NNB) {
            int n = tid - 128;
            s_nb[n] = nbr[v*NNB + n];
            int raw = bytemode ? (int)mskb[v*NNB + n] : mski[v*NNB + n];
            s_m[n]  = (raw != 0) ? 1.0f : 0.0f;
        }
        if (tid >= 160 && tid < 160 + NNB) {
            int n = tid - 160;
            float u0 = rel[(v*NNB + n)*2 + 0];
            float u1 = rel[(v*NNB + n)*2 + 1];
            s_scal[n*6+0] = 1.0f;  s_scal[n*6+1] = u0;       s_scal[n*6+2] = u1;
            s_scal[n*6+3] = u0*u0; s_scal[n*6+4] = 2.f*u0*u1; s_scal[n*6+5] = u1*u1;
        }
        for (int k = tid; k < NNB*64; k += 256) s_pt[k] = pt[v*(NNB*64) + k];
        __syncthreads();

        for (int k = tid; k < NNB*128; k += 256) {
            int n = k >> 7;
            s_xn[k] = x[s_nb[n]*128 + (k & 127)];
        }
        __syncthreads();

        // --- f[n][c][i] = m[n] * sum_j pt[n,i,j] * xn[n,c,j] ---------------
        for (int k = tid; k < NNB*128; k += 256) {
            int n = k >> 7, r = k & 127, c = r >> 3, i = r & 7;
            const float4* pr = (const float4*)&s_pt[n*64 + i*8];
            const float4* xr = (const float4*)&s_xn[n*128 + c*8];
            float4 p0 = pr[0], p1 = pr[1], x0 = xr[0], x1 = xr[1];
            float s = p0.x*x0.x + p0.y*x0.y + p0.z*x0.z + p0.w*x0.w
                    + p1.x*x1.x + p1.y*x1.y + p1.z*x1.z + p1.w*x1.w;
            s_f[k] = s_m[n] * s;
        }
        __syncthreads();

        // --- Q[h][i], K[n][h][i] (circulant coeff indexing) ----------------
        if (tid < 32) {
            int h = tid >> 3, i = tid & 7;
            float s = 0.f;
            for (int c = 0; c < NC; ++c) {
                const float* qr = &s_qc[h*128 + c*8];
                const float* xr = &s_x[c*8];
                #pragma unroll
                for (int j = 0; j < 8; ++j) s += qr[(j - i + 8) & 7] * xr[j];
            }
            s_Q[tid] = s;
        }
        for (int k = tid; k < NNB*32; k += 256) {
            int n = k >> 5, h = (k >> 3) & 3, i = k & 7;
            float s = 0.f;
            for (int c = 0; c < NC; ++c) {
                const float* kr = &s_kc[h*128 + c*8];
                const float* fr = &s_f[n*128 + c*8];
                #pragma unroll
                for (int j = 0; j < 8; ++j) s += kr[(j - i + 8) & 7] * fr[j];
            }
            s_K[k] = s;
        }
        __syncthreads();

        if (tid < NNB*4) {
            int n = tid >> 2, h = tid & 3;
            float s = 0.f;
            #pragma unroll
            for (int i = 0; i < 8; ++i)
                s += fmaxf(0.f, s_Q[h*8 + i] + s_K[n*32 + h*8 + i]);
            s_sc[tid] = 0.125f * s * s_m[n];
        }
        __syncthreads();

        if (tid < 4) {
            float d = 0.f;
            for (int n = 0; n < NNB; ++n) d += s_sc[n*4 + tid];
            s_den[tid] = d;
        } else if (tid == 4) {
            float nv = 0.f;
            for (int n = 0; n < NNB; ++n) nv += s_m[n];
            s_nv[0] = fmaxf(nv, 1.0f);
        }
        __syncthreads();

        // --- w[n][h*6+p] = attn * scal ------------------------------------
        for (int k = tid; k < NNB*24; k += 256) {
            int n = k / 24, r = k % 24, h = r / 6, p = r % 6;
            float den = s_den[h];
            float attn = (den < 1e-6f) ? (s_m[n] / s_nv[0])
                                       : (s_sc[n*4 + h] / fmaxf(den, 1e-6f));
            s_w[k] = attn * s_scal[n*6 + p];
        }
        __syncthreads();

        // --- G[h][p][c][j] -------------------------------------------------
        for (int k = tid; k < 768; k += 256) {
            int hp = k >> 5, cj4 = k & 31;
            float4 acc = {0.f, 0.f, 0.f, 0.f};
            #pragma unroll
            for (int n = 0; n < NNB; ++n) {
                float w = s_w[n*24 + hp];
                float4 fv = ((const float4*)&s_f[n*128])[cj4];
                acc.x += w*fv.x; acc.y += w*fv.y; acc.z += w*fv.z; acc.w += w*fv.w;
            }
            int h = hp / 6, p = hp % 6;
            ((float4*)&s_G[h*768 + p*128])[cj4] = acc;
        }
        __syncthreads();

        // --- head -> s_head[cp*9 + j] (A from registers) -------------------
        {
            int h = tid >> 7, c = (tid >> 3) & 15;
            float s = 0.f;
            #pragma unroll
            for (int j = 0; j < 8; ++j)
                #pragma unroll
                for (int p = 0; p < 6; ++p)
                    s += a0[j*6 + p] * s_G[h*768 + p*128 + c*8 + j];
            s_head[(tid >> 3)*9 + (tid & 7)] = s;

            int k1 = tid + 256;
            h = k1 >> 7; c = (k1 >> 3) & 15;
            float s2 = 0.f;
            #pragma unroll
            for (int j = 0; j < 8; ++j)
                #pragma unroll
                for (int p = 0; p < 6; ++p)
                    s2 += a1[j*6 + p] * s_G[h*768 + p*128 + c*8 + j];
            s_head[(k1 >> 3)*9 + (k1 & 7)] = s2;
        }
        __syncthreads();

        // --- projection (wm from registers), partials into s_part=s_G -----
        {
            const int o = tid >> 4, g4 = tid & 15;
            float acc[8] = {0,0,0,0,0,0,0,0};
            #pragma unroll
            for (int q = 0; q < 4; ++q) {
                int cp = g4*4 + q;
                float hr[8];
                #pragma unroll
                for (int j = 0; j < 8; ++j) hr[j] = s_head[cp*9 + j];
                #pragma unroll
                for (int d = 0; d < 8; ++d) {
                    float w = wreg[q*8 + d];
                    #pragma unroll
                    for (int i = 0; i < 8; ++i) acc[i] += w * hr[(i + d) & 7];
                }
            }
            float* s_part = s_G;
            #pragma unroll
            for (int i = 0; i < 8; ++i) s_part[o*128 + g4*8 + i] = acc[i];
        }
        __syncthreads();

        if (tid < 128) {
            int o = tid >> 3, i = tid & 7;
            const float* s_part = s_G;
            float s = 0.f;
            #pragma unroll
            for (int g4 = 0; g4 < 16; ++g4) s += s_part[o*128 + g4*8 + i];
            out[v*128 + o*8 + i] = s;
        }
        __syncthreads();
    }
}

extern "C" void kernel_launch(void* const* d_in, const int* in_sizes, int n_in,
                              void* d_out, int out_size, void* d_ws, size_t ws_size,
                              hipStream_t stream)
{
    const float* x   = (const float*)d_in[0];
    const int*   nbr = (const int*)d_in[1];
    const unsigned char* msk = (const unsigned char*)d_in[2];
    const float* pt  = (const float*)d_in[3];
    const float* rel = (const float*)d_in[4];
    // d_in[5] reg_basis: circulant structure exploited analytically
    const float* vb1 = (const float*)d_in[6];
    const float* vb2 = (const float*)d_in[7];
    const float* qc  = (const float*)d_in[8];
    const float* kc  = (const float*)d_in[9];
    const float* v0p = (const float*)d_in[10];
    const float* v1p = (const float*)d_in[11];
    const float* v2p = (const float*)d_in[12];
    const float* wm  = (const float*)d_in[13];

    int*   flag = (int*)d_ws;
    float* A    = (float*)d_ws + 64;
    float* out  = (float*)d_out;

    hipMemsetAsync(d_ws, 0, 256, stream);
    hipLaunchKernelGGL(kdetect, dim3(64),   dim3(256), 0, stream, msk, flag);
    hipLaunchKernelGGL(ksetup,  dim3(96),   dim3(256), 0, stream, v0p, v1p, v2p, vb1, vb2, A);
    hipLaunchKernelGGL(kmain,   dim3(NV/VPB), dim3(256), 0, stream,
                       x, nbr, msk, pt, rel, qc, kc, A, wm, flag, out);
}

// Round 4
// 321.898 us; speedup vs baseline: 4.0145x; 4.0145x over previous
//
#include <hip/hip_runtime.h>

#define NV  20000
#define NNB 12
#define NC  16
#define NH  4
#define VC  4            // vertices concurrent per block
#define GRID (NV/VC)     // 5000

// ---- LDS float offsets (all 16B-aligned) ----
#define OFF_X    0        // [v*132 + c*8 + j]    528
#define OFF_PT   528      // [vn*68 + i*8 + j]   3264 (aliased by HEAD after P1)
#define OFF_HEAD 528      // [v*520 + hc*8 + i]  2080
#define OFF_F    3792     // [vn*132 + c*8 + j]  6336
#define OFF_QC   10128    // [h*132 + c*8 + s]    528
#define OFF_KC   10656    //                      528
#define OFF_Q    11184    // [(v*4+h)*8 + i]      128
#define OFF_SC   11312    // [vn*4 + h]           192
#define OFF_DEN  11504    // [v*4 + h]             16
#define OFF_NV   11520    // [v]                    4
#define OFF_AT   11524    // [vn*4 + h]           192
#define OFF_SCAL 11716    // [vn*8 + p]           384
#define OFF_NB   12100    // int [vn]              48
#define OFF_M    12148    // [vn]                  48
#define SMEM_FL  12196

#define LD8(dst, off) { const float4 _a = *(const float4*)&smem[(off)]; \
                        const float4 _b = *(const float4*)&smem[(off)+4]; \
                        dst[0]=_a.x; dst[1]=_a.y; dst[2]=_a.z; dst[3]=_a.w; \
                        dst[4]=_b.x; dst[5]=_b.y; dst[6]=_b.z; dst[7]=_b.w; }
#define ST8(off, src) { *(float4*)&smem[(off)]   = make_float4(src[0],src[1],src[2],src[3]); \
                        *(float4*)&smem[(off)+4] = make_float4(src[4],src[5],src[6],src[7]); }

// ---------------------------------------------------------------------------
// Mask dtype detect (unchanged from R3 — it passed). flag=1 -> byte storage.
// ---------------------------------------------------------------------------
__global__ __launch_bounds__(256) void kdetect(const unsigned char* __restrict__ m,
                                               int* __restrict__ flag)
{
    __shared__ int s_nz;
    if (threadIdx.x == 0) s_nz = 0;
    __syncthreads();
    int nz = 0;
    for (int k = blockIdx.x * 256 + threadIdx.x; k < NV * NNB; k += gridDim.x * 256) {
        if ((k & 3) != 0 && m[k] != 0) nz = 1;
    }
    if (nz) atomicOr(&s_nz, 1);
    __syncthreads();
    if (threadIdx.x == 0 && s_nz) atomicOr(flag, 1);
}

// ---------------------------------------------------------------------------
// A4[((p*8 + i)*64 + hc)*8 + j] = A(h,c,i,j,p); hc = h*16+c
//   p=0: v0p[h,c,(j-i)&7]; p=1,2: sum_b v1p*vb1[b,p-1,i,j]; p=3..5: v2p*vb2
// ---------------------------------------------------------------------------
__global__ __launch_bounds__(256) void ksetup(
    const float* __restrict__ v0p, const float* __restrict__ v1p,
    const float* __restrict__ v2p, const float* __restrict__ vb1,
    const float* __restrict__ vb2, float* __restrict__ A4)
{
    int idx = blockIdx.x * 256 + threadIdx.x;
    if (idx >= 24576) return;
    int j = idx & 7;
    int t = idx >> 3;
    int hc = t & 63; t >>= 6;
    int i = t & 7;
    int p = t >> 3;
    int h = hc >> 4, c = hc & 15;
    float s = 0.f;
    if (p == 0) {
        s = v0p[h*128 + c*8 + ((j - i + 8) & 7)];
    } else if (p <= 2) {
        int o = p - 1;
        #pragma unroll
        for (int b = 0; b < 8; ++b)
            s += v1p[h*128 + c*8 + b] * vb1[((b*2 + o)*8 + i)*8 + j];
    } else {
        int o = p - 3;
        #pragma unroll
        for (int b = 0; b < 8; ++b)
            s += v2p[h*128 + c*8 + b] * vb2[((b*3 + o)*8 + i)*8 + j];
    }
    A4[idx] = s;
}

// ---------------------------------------------------------------------------
// Fused main: 4 vertices per block, single pass, 7 barriers.
// ---------------------------------------------------------------------------
__global__ __launch_bounds__(256) void kmain(
    const float* __restrict__ x, const int* __restrict__ nbr,
    const unsigned char* __restrict__ mskb, const float* __restrict__ pt,
    const float* __restrict__ rel, const float* __restrict__ qc,
    const float* __restrict__ kc, const float* __restrict__ A4,
    const float* __restrict__ wm, const int* __restrict__ flagp,
    float* __restrict__ out)
{
    const int tid = threadIdx.x;
    const int vbase = blockIdx.x * VC;
    const int bytemode = flagp[0];
    const int* mski = (const int*)mskb;

    __shared__ __align__(16) float smem[SMEM_FL];

    // ---- P0: stage ----
    for (int k = tid; k < VC*128; k += 256)
        smem[OFF_X + (k>>7)*132 + (k&127)] = x[(vbase + (k>>7))*128 + (k&127)];
    for (int k = tid; k < VC*NNB*64; k += 256)
        smem[OFF_PT + (k>>6)*68 + (k&63)] = pt[vbase*(NNB*64) + k];
    for (int k = tid; k < 512; k += 256) {
        smem[OFF_QC + (k>>7)*132 + (k&127)] = qc[k];
        smem[OFF_KC + (k>>7)*132 + (k&127)] = kc[k];
    }
    if (tid < VC*NNB) {
        int gi = vbase*NNB + tid;
        ((int*)smem)[OFF_NB + tid] = nbr[gi];
        int raw = bytemode ? (int)mskb[gi] : mski[gi];
        smem[OFF_M + tid] = raw ? 1.0f : 0.0f;
    }
    if (tid >= 64 && tid < 64 + VC*NNB) {
        int vn = tid - 64;
        float u0 = rel[(vbase*NNB + vn)*2 + 0];
        float u1 = rel[(vbase*NNB + vn)*2 + 1];
        smem[OFF_SCAL+vn*8+0] = 1.0f;
        smem[OFF_SCAL+vn*8+1] = u0;
        smem[OFF_SCAL+vn*8+2] = u1;
        smem[OFF_SCAL+vn*8+3] = u0*u0;
        smem[OFF_SCAL+vn*8+4] = 2.0f*u0*u1;
        smem[OFF_SCAL+vn*8+5] = u1*u1;
        smem[OFF_SCAL+vn*8+6] = 0.0f;
        smem[OFF_SCAL+vn*8+7] = 0.0f;
    }
    __syncthreads();

    // ---- P1: f[vn][c][slot] = m * sum_j pt[vn,slot,j] * x[nb][c][j] ----
    if (tid < 192) {
        const int vn = tid >> 2, cq = tid & 3;
        const int nb = ((const int*)smem)[OFF_NB + vn];
        const float m = smem[OFF_M + vn];
        const float4* xg = (const float4*)(x + nb*128 + cq*32);
        float xnf[32];
        #pragma unroll
        for (int q = 0; q < 8; ++q) {
            float4 tv = xg[q];
            xnf[q*4+0]=tv.x; xnf[q*4+1]=tv.y; xnf[q*4+2]=tv.z; xnf[q*4+3]=tv.w;
        }
        float acc[4][8];
        #pragma unroll
        for (int c4 = 0; c4 < 4; ++c4)
            #pragma unroll
            for (int i = 0; i < 8; ++i) acc[c4][i] = 0.f;
        #pragma unroll
        for (int i = 0; i < 8; ++i) {
            float pj[8]; LD8(pj, OFF_PT + vn*68 + i*8);
            #pragma unroll
            for (int c4 = 0; c4 < 4; ++c4)
                #pragma unroll
                for (int j = 0; j < 8; ++j)
                    acc[c4][i] += pj[j] * xnf[c4*8 + j];
        }
        #pragma unroll
        for (int c4 = 0; c4 < 4; ++c4) {
            int c = cq*4 + c4;
            float w[8];
            #pragma unroll
            for (int i = 0; i < 8; ++i) w[i] = m * acc[c4][i];
            ST8(OFF_F + vn*132 + c*8, w);
        }
    }
    __syncthreads();

    // ---- P2: Q (rotation-in-registers + shuffle reduce) ----
    float K8[8] = {0,0,0,0,0,0,0,0};
    if (tid < 128) {
        const int cs = tid & 7, vh = tid >> 3, v = vh >> 2, h = vh & 3;
        float Q8[8] = {0,0,0,0,0,0,0,0};
        #pragma unroll
        for (int t = 0; t < 2; ++t) {
            int c = cs*2 + t;
            float xv[8]; LD8(xv, OFF_X + v*132 + c*8);
            float qv[8]; LD8(qv, OFF_QC + h*132 + c*8);
            #pragma unroll
            for (int s = 0; s < 8; ++s)
                #pragma unroll
                for (int i = 0; i < 8; ++i)
                    Q8[i] += qv[s] * xv[(i+s)&7];
        }
        #pragma unroll
        for (int msk = 1; msk < 8; msk <<= 1)
            #pragma unroll
            for (int i = 0; i < 8; ++i) Q8[i] += __shfl_xor(Q8[i], msk, 64);
        if (cs == 0) { ST8(OFF_Q + vh*8, Q8); }
    }
    // ---- P3: K (kept in registers) ----
    if (tid < 192) {
        const int vn = tid >> 2, h = tid & 3;
        #pragma unroll 2
        for (int c = 0; c < 16; ++c) {
            float kv[8]; LD8(kv, OFF_KC + h*132 + c*8);
            float fv[8]; LD8(fv, OFF_F + vn*132 + c*8);
            #pragma unroll
            for (int s = 0; s < 8; ++s)
                #pragma unroll
                for (int i = 0; i < 8; ++i)
                    K8[i] += kv[s] * fv[(i+s)&7];
        }
    }
    __syncthreads();

    // ---- P4: scores ----
    if (tid < 192) {
        const int vn = tid >> 2, h = tid & 3, v = vn / 12;
        float q[8]; LD8(q, OFF_Q + (v*4+h)*8);
        float s = 0.f;
        #pragma unroll
        for (int i = 0; i < 8; ++i) s += fmaxf(0.f, q[i] + K8[i]);
        smem[OFF_SC + vn*4 + h] = 0.125f * s * smem[OFF_M + vn];
    }
    __syncthreads();

    // ---- P5a: den, n_valid ----
    if (tid < 16) {
        int v = tid >> 2, h = tid & 3;
        float d = 0.f;
        for (int n = 0; n < 12; ++n) d += smem[OFF_SC + (v*12+n)*4 + h];
        smem[OFF_DEN + tid] = d;
        if (h == 0) {
            float nv = 0.f;
            for (int n = 0; n < 12; ++n) nv += smem[OFF_M + v*12 + n];
            smem[OFF_NV + v] = fmaxf(nv, 1.0f);
        }
    }
    __syncthreads();
    // ---- P5b: attn ----
    if (tid < 192) {
        const int vn = tid >> 2, h = tid & 3, v = vn / 12;
        float den = smem[OFF_DEN + v*4 + h];
        float at = (den < 1e-6f) ? (smem[OFF_M + vn] / smem[OFF_NV + v])
                                 : (smem[OFF_SC + vn*4 + h] / fmaxf(den, 1e-6f));
        smem[OFF_AT + vn*4 + h] = at;
    }
    __syncthreads();

    // ---- P6: G (registers only!) + head accumulation with A from L2 ----
    const int v6 = tid >> 6, h6 = (tid >> 4) & 3, c6 = tid & 15, hc = tid & 63;
    float G[6][8];
    #pragma unroll
    for (int p = 0; p < 6; ++p)
        #pragma unroll
        for (int j = 0; j < 8; ++j) G[p][j] = 0.f;
    for (int n = 0; n < 12; ++n) {
        int vn = v6*12 + n;
        float at = smem[OFF_AT + vn*4 + h6];
        float sc[8]; LD8(sc, OFF_SCAL + vn*8);
        float fv[8]; LD8(fv, OFF_F + vn*132 + c6*8);
        #pragma unroll
        for (int p = 0; p < 6; ++p) {
            float w = at * sc[p];
            #pragma unroll
            for (int j = 0; j < 8; ++j) G[p][j] += w * fv[j];
        }
    }
    float hd[8] = {0,0,0,0,0,0,0,0};
    #pragma unroll
    for (int p = 0; p < 6; ++p) {
        #pragma unroll
        for (int i = 0; i < 8; ++i) {
            const float4 a0 = *(const float4*)&A4[(((p*8+i)*64 + hc)*8)];
            const float4 a1 = *(const float4*)&A4[(((p*8+i)*64 + hc)*8) + 4];
            hd[i] += a0.x*G[p][0] + a0.y*G[p][1] + a0.z*G[p][2] + a0.w*G[p][3]
                   + a1.x*G[p][4] + a1.y*G[p][5] + a1.z*G[p][6] + a1.w*G[p][7];
        }
    }
    // ---- P7: head -> LDS (aliases dead pt region) ----
    ST8(OFF_HEAD + v6*520 + hc*8, hd);
    __syncthreads();

    // ---- P8: projection (rotation-in-registers, wm from L1/L2) ----
    {
        const int v = tid >> 6, o = (tid >> 2) & 15, cs = tid & 3;
        float acc[8] = {0,0,0,0,0,0,0,0};
        #pragma unroll 2
        for (int cc = 0; cc < 16; ++cc) {
            int cp = cc*4 + cs;
            float hh[8]; LD8(hh, OFF_HEAD + v*520 + cp*8);
            const float4 w0 = *(const float4*)&wm[(o*64 + cp)*8];
            const float4 w1 = *(const float4*)&wm[(o*64 + cp)*8 + 4];
            float wv[8] = {w0.x,w0.y,w0.z,w0.w,w1.x,w1.y,w1.z,w1.w};
            #pragma unroll
            for (int d = 0; d < 8; ++d)
                #pragma unroll
                for (int i = 0; i < 8; ++i)
                    acc[i] += wv[d] * hh[(i+d)&7];
        }
        #pragma unroll
        for (int msk = 1; msk < 4; msk <<= 1)
            #pragma unroll
            for (int i = 0; i < 8; ++i) acc[i] += __shfl_xor(acc[i], msk, 64);
        if (cs == 0) {
            float* op = out + (vbase + v)*128 + o*8;
            *(float4*)op       = make_float4(acc[0],acc[1],acc[2],acc[3]);
            *(float4*)(op + 4) = make_float4(acc[4],acc[5],acc[6],acc[7]);
        }
    }
}

extern "C" void kernel_launch(void* const* d_in, const int* in_sizes, int n_in,
                              void* d_out, int out_size, void* d_ws, size_t ws_size,
                              hipStream_t stream)
{
    const float* x   = (const float*)d_in[0];
    const int*   nbr = (const int*)d_in[1];
    const unsigned char* msk = (const unsigned char*)d_in[2];
    const float* pt  = (const float*)d_in[3];
    const float* rel = (const float*)d_in[4];
    // d_in[5] reg_basis: circulant structure exploited analytically
    const float* vb1 = (const float*)d_in[6];
    const float* vb2 = (const float*)d_in[7];
    const float* qc  = (const float*)d_in[8];
    const float* kc  = (const float*)d_in[9];
    const float* v0p = (const float*)d_in[10];
    const float* v1p = (const float*)d_in[11];
    const float* v2p = (const float*)d_in[12];
    const float* wm  = (const float*)d_in[13];

    int*   flag = (int*)d_ws;
    float* A4   = (float*)d_ws + 64;
    float* outp = (float*)d_out;

    hipMemsetAsync(d_ws, 0, 256, stream);
    hipLaunchKernelGGL(kdetect, dim3(64),   dim3(256), 0, stream, msk, flag);
    hipLaunchKernelGGL(ksetup,  dim3(96),   dim3(256), 0, stream, v0p, v1p, v2p, vb1, vb2, A4);
    hipLaunchKernelGGL(kmain,   dim3(GRID), dim3(256), 0, stream,
                       x, nbr, msk, pt, rel, qc, kc, A4, wm, flag, outp);
}

// Round 6
// 277.282 us; speedup vs baseline: 4.6604x; 1.1609x over previous
//
#include <hip/hip_runtime.h>

#define NV  20000
#define NNB 12
#define NC  16
#define NH  4
#define VC  4            // vertices concurrent per block
#define GRID (NV/VC)     // 5000

// ---- LDS float offsets ----
// R region (3264 fl): P0..P1: pt[vn*68+i*8+j]
//                     after P1: qc(528) | kc(528) | Q(128) | head(2080)
#define OFF_R    0
#define OFF_QC   0         // [h*132 + c*8 + s]
#define OFF_KC   528
#define OFF_Q    1056      // [(v*4+h)*8 + i]
#define OFF_HEAD 1184      // [v*520 + hc*8 + i]
#define OFF_F    3264      // [vn*132 + c*8 + j]   6336
#define OFF_SC   9600      // [vn*4 + h] scores, then attn in-place (192)
#define OFF_DEN  9792      // [v*4 + h]  (16)
#define OFF_NV   9808      // [v]        (8 incl pad)
#define OFF_S4   9816      // [vn*4 + p0..3]  (192)
#define OFF_S2   10008     // [vn*2 + p4..5]  (96)
#define OFF_NB   10104     // int [vn]        (48)
#define OFF_M    10152     // [vn]            (48)
#define SMEM_FL  10200     // 40800 bytes -> 4 blocks/CU

#define LD8(dst, off) { const float4 _a = *(const float4*)&smem[(off)]; \
                        const float4 _b = *(const float4*)&smem[(off)+4]; \
                        dst[0]=_a.x; dst[1]=_a.y; dst[2]=_a.z; dst[3]=_a.w; \
                        dst[4]=_b.x; dst[5]=_b.y; dst[6]=_b.z; dst[7]=_b.w; }
#define ST8(off, src) { *(float4*)&smem[(off)]   = make_float4(src[0],src[1],src[2],src[3]); \
                        *(float4*)&smem[(off)+4] = make_float4(src[4],src[5],src[6],src[7]); }

// ---------------------------------------------------------------------------
// Merged setup + mask-dtype detect. Blocks 0..95: A4 table; 96..159: detect.
// A4[((p*8 + i)*64 + hc)*8 + j] = A(h,c,i,j,p); hc = h*16+c.
// ---------------------------------------------------------------------------
__global__ __launch_bounds__(256) void kprep(
    const float* __restrict__ v0p, const float* __restrict__ v1p,
    const float* __restrict__ v2p, const float* __restrict__ vb1,
    const float* __restrict__ vb2, float* __restrict__ A4,
    const unsigned char* __restrict__ m, int* __restrict__ flag)
{
    const int b = blockIdx.x, tid = threadIdx.x;
    if (b < 96) {
        int idx = b * 256 + tid;
        int j = idx & 7;
        int t = idx >> 3;
        int hc = t & 63; t >>= 6;
        int i = t & 7;
        int p = t >> 3;
        int h = hc >> 4, c = hc & 15;
        float s = 0.f;
        if (p == 0) {
            s = v0p[h*128 + c*8 + ((j - i + 8) & 7)];
        } else if (p <= 2) {
            int o = p - 1;
            #pragma unroll
            for (int bb = 0; bb < 8; ++bb)
                s += v1p[h*128 + c*8 + bb] * vb1[((bb*2 + o)*8 + i)*8 + j];
        } else {
            int o = p - 3;
            #pragma unroll
            for (int bb = 0; bb < 8; ++bb)
                s += v2p[h*128 + c*8 + bb] * vb2[((bb*3 + o)*8 + i)*8 + j];
        }
        A4[idx] = s;
    } else {
        __shared__ int s_nz;
        if (tid == 0) s_nz = 0;
        __syncthreads();
        int nz = 0;
        for (int k = (b - 96) * 256 + tid; k < NV * NNB; k += 64 * 256) {
            if ((k & 3) != 0 && m[k] != 0) nz = 1;
        }
        if (nz) atomicOr(&s_nz, 1);
        __syncthreads();
        if (tid == 0 && s_nz) atomicOr(flag, 1);   // 1 => byte storage
    }
}

// ---------------------------------------------------------------------------
// Fused main: 4 vertices per block, 8 barriers, 40800 B LDS (4 blocks/CU).
// ---------------------------------------------------------------------------
__global__ __launch_bounds__(256, 4) void kmain(
    const float* __restrict__ x, const int* __restrict__ nbr,
    const unsigned char* __restrict__ mskb, const float* __restrict__ pt,
    const float* __restrict__ rel, const float* __restrict__ qc,
    const float* __restrict__ kc, const float* __restrict__ A4,
    const float* __restrict__ wm, const int* __restrict__ flagp,
    float* __restrict__ out)
{
    const int tid = threadIdx.x;
    const int vbase = blockIdx.x * VC;
    const int bytemode = flagp[0];
    const int* mski = (const int*)mskb;

    __shared__ __align__(16) float smem[SMEM_FL];

    // ---- P0: stage pt, nb, m, scal ----
    for (int k = tid; k < VC*NNB*64; k += 256)
        smem[OFF_R + (k>>6)*68 + (k&63)] = pt[vbase*(NNB*64) + k];
    if (tid < VC*NNB) {
        int gi = vbase*NNB + tid;
        ((int*)smem)[OFF_NB + tid] = nbr[gi];
        int raw = bytemode ? (int)mskb[gi] : mski[gi];
        smem[OFF_M + tid] = raw ? 1.0f : 0.0f;
    }
    if (tid >= 64 && tid < 64 + VC*NNB) {
        int vn = tid - 64;
        float u0 = rel[(vbase*NNB + vn)*2 + 0];
        float u1 = rel[(vbase*NNB + vn)*2 + 1];
        smem[OFF_S4+vn*4+0] = 1.0f;
        smem[OFF_S4+vn*4+1] = u0;
        smem[OFF_S4+vn*4+2] = u1;
        smem[OFF_S4+vn*4+3] = u0*u0;
        smem[OFF_S2+vn*2+0] = 2.0f*u0*u1;
        smem[OFF_S2+vn*2+1] = u1*u1;
    }
    __syncthreads();

    // ---- P1: f[vn][c][i] = m * sum_j pt[vn,i,j] * x[nb][c][j] ----
    if (tid < 192) {
        const int vn = tid >> 2, cq = tid & 3;
        const int nb = ((const int*)smem)[OFF_NB + vn];
        const float m = smem[OFF_M + vn];
        const float4* xg = (const float4*)(x + nb*128 + cq*32);
        float xnf[32];
        #pragma unroll
        for (int q = 0; q < 8; ++q) {
            float4 tv = xg[q];
            xnf[q*4+0]=tv.x; xnf[q*4+1]=tv.y; xnf[q*4+2]=tv.z; xnf[q*4+3]=tv.w;
        }
        float acc[4][8];
        #pragma unroll
        for (int c4 = 0; c4 < 4; ++c4)
            #pragma unroll
            for (int i = 0; i < 8; ++i) acc[c4][i] = 0.f;
        #pragma unroll
        for (int i = 0; i < 8; ++i) {
            float pj[8]; LD8(pj, OFF_R + vn*68 + i*8);
            #pragma unroll
            for (int c4 = 0; c4 < 4; ++c4)
                #pragma unroll
                for (int j = 0; j < 8; ++j)
                    acc[c4][i] += pj[j] * xnf[c4*8 + j];
        }
        #pragma unroll
        for (int c4 = 0; c4 < 4; ++c4) {
            int c = cq*4 + c4;
            float w[8];
            #pragma unroll
            for (int i = 0; i < 8; ++i) w[i] = m * acc[c4][i];
            ST8(OFF_F + vn*132 + c*8, w);
        }
    }
    __syncthreads();

    // ---- P1b: restage qc/kc into dead pt region ----
    for (int k = tid; k < 512; k += 256) {
        smem[OFF_QC + (k>>7)*132 + (k&127)] = qc[k];
        smem[OFF_KC + (k>>7)*132 + (k&127)] = kc[k];
    }
    __syncthreads();

    // ---- P2: Q (x from global, rotation-in-registers + shuffle reduce) ----
    float K8[8] = {0,0,0,0,0,0,0,0};
    if (tid < 128) {
        const int cs = tid & 7, vh = tid >> 3, v = vh >> 2, h = vh & 3;
        const float* xrow = x + (vbase + v)*128;
        float Q8[8] = {0,0,0,0,0,0,0,0};
        #pragma unroll
        for (int t = 0; t < 2; ++t) {
            int c = cs*2 + t;
            const float4 xa = *(const float4*)(xrow + c*8);
            const float4 xb = *(const float4*)(xrow + c*8 + 4);
            float xv[8] = {xa.x,xa.y,xa.z,xa.w,xb.x,xb.y,xb.z,xb.w};
            float qv[8]; LD8(qv, OFF_QC + h*132 + c*8);
            #pragma unroll
            for (int s = 0; s < 8; ++s)
                #pragma unroll
                for (int i = 0; i < 8; ++i)
                    Q8[i] += qv[s] * xv[(i+s)&7];
        }
        #pragma unroll
        for (int msk = 1; msk < 8; msk <<= 1)
            #pragma unroll
            for (int i = 0; i < 8; ++i) Q8[i] += __shfl_xor(Q8[i], msk, 64);
        if (cs == 0) { ST8(OFF_Q + vh*8, Q8); }
    }
    // ---- P3: K (kept in registers) ----
    if (tid < 192) {
        const int vn = tid >> 2, h = tid & 3;
        #pragma unroll 2
        for (int c = 0; c < 16; ++c) {
            float kv[8]; LD8(kv, OFF_KC + h*132 + c*8);
            float fv[8]; LD8(fv, OFF_F + vn*132 + c*8);
            #pragma unroll
            for (int s = 0; s < 8; ++s)
                #pragma unroll
                for (int i = 0; i < 8; ++i)
                    K8[i] += kv[s] * fv[(i+s)&7];
        }
    }
    __syncthreads();

    // ---- P4: scores ----
    if (tid < 192) {
        const int vn = tid >> 2, h = tid & 3, v = vn / 12;
        float q[8]; LD8(q, OFF_Q + (v*4+h)*8);
        float s = 0.f;
        #pragma unroll
        for (int i = 0; i < 8; ++i) s += fmaxf(0.f, q[i] + K8[i]);
        smem[OFF_SC + vn*4 + h] = 0.125f * s * smem[OFF_M + vn];
    }
    __syncthreads();

    // ---- P5a: den, n_valid ----
    if (tid < 16) {
        int v = tid >> 2, h = tid & 3;
        float d = 0.f;
        for (int n = 0; n < 12; ++n) d += smem[OFF_SC + (v*12+n)*4 + h];
        smem[OFF_DEN + tid] = d;
        if (h == 0) {
            float nv = 0.f;
            for (int n = 0; n < 12; ++n) nv += smem[OFF_M + v*12 + n];
            smem[OFF_NV + v] = fmaxf(nv, 1.0f);
        }
    }
    __syncthreads();
    // ---- P5b: attn in-place over SC ----
    if (tid < 192) {
        const int vn = tid >> 2, h = tid & 3, v = vn / 12;
        float den = smem[OFF_DEN + v*4 + h];
        float at = (den < 1e-6f) ? (smem[OFF_M + vn] / smem[OFF_NV + v])
                                 : (smem[OFF_SC + vn*4 + h] / fmaxf(den, 1e-6f));
        __syncthreads();
        smem[OFF_SC + vn*4 + h] = at;
    } else {
        __syncthreads();
    }
    __syncthreads();

    // ---- P6: G (registers only) + head with A4 from L2 ----
    const int v6 = tid >> 6, h6 = (tid >> 4) & 3, c6 = tid & 15, hc = tid & 63;
    float G[6][8];
    #pragma unroll
    for (int p = 0; p < 6; ++p)
        #pragma unroll
        for (int j = 0; j < 8; ++j) G[p][j] = 0.f;
    for (int n = 0; n < 12; ++n) {
        int vn = v6*12 + n;
        float at = smem[OFF_SC + vn*4 + h6];
        const float4 s4 = *(const float4*)&smem[OFF_S4 + vn*4];
        const float2 s2 = *(const float2*)&smem[OFF_S2 + vn*2];
        float fv[8]; LD8(fv, OFF_F + vn*132 + c6*8);
        float w[6] = {at*s4.x, at*s4.y, at*s4.z, at*s4.w, at*s2.x, at*s2.y};
        #pragma unroll
        for (int p = 0; p < 6; ++p)
            #pragma unroll
            for (int j = 0; j < 8; ++j) G[p][j] += w[p] * fv[j];
    }
    float hd[8] = {0,0,0,0,0,0,0,0};
    #pragma unroll
    for (int p = 0; p < 6; ++p) {
        #pragma unroll
        for (int i = 0; i < 8; ++i) {
            const float4 a0 = *(const float4*)&A4[(((p*8+i)*64 + hc)*8)];
            const float4 a1 = *(const float4*)&A4[(((p*8+i)*64 + hc)*8) + 4];
            hd[i] += a0.x*G[p][0] + a0.y*G[p][1] + a0.z*G[p][2] + a0.w*G[p][3]
                   + a1.x*G[p][4] + a1.y*G[p][5] + a1.z*G[p][6] + a1.w*G[p][7];
        }
    }
    // ---- P7: head -> LDS (dead qc/kc/pt region) ----
    ST8(OFF_HEAD + v6*520 + hc*8, hd);
    __syncthreads();

    // ---- P8: projection (rotation-in-registers, wm from L1/L2) ----
    {
        const int v = tid >> 6, o = (tid >> 2) & 15, cs = tid & 3;
        float acc[8] = {0,0,0,0,0,0,0,0};
        #pragma unroll 2
        for (int cc = 0; cc < 16; ++cc) {
            int cp = cc*4 + cs;
            float hh[8]; LD8(hh, OFF_HEAD + v*520 + cp*8);
            const float4 w0 = *(const float4*)&wm[(o*64 + cp)*8];
            const float4 w1 = *(const float4*)&wm[(o*64 + cp)*8 + 4];
            float wv[8] = {w0.x,w0.y,w0.z,w0.w,w1.x,w1.y,w1.z,w1.w};
            #pragma unroll
            for (int d = 0; d < 8; ++d)
                #pragma unroll
                for (int i = 0; i < 8; ++i)
                    acc[i] += wv[d] * hh[(i+d)&7];
        }
        #pragma unroll
        for (int msk = 1; msk < 4; msk <<= 1)
            #pragma unroll
            for (int i = 0; i < 8; ++i) acc[i] += __shfl_xor(acc[i], msk, 64);
        if (cs == 0) {
            float* op = out + (vbase + v)*128 + o*8;
            *(float4*)op       = make_float4(acc[0],acc[1],acc[2],acc[3]);
            *(float4*)(op + 4) = make_float4(acc[4],acc[5],acc[6],acc[7]);
        }
    }
}

extern "C" void kernel_launch(void* const* d_in, const int* in_sizes, int n_in,
                              void* d_out, int out_size, void* d_ws, size_t ws_size,
                              hipStream_t stream)
{
    const float* x   = (const float*)d_in[0];
    const int*   nbr = (const int*)d_in[1];
    const unsigned char* msk = (const unsigned char*)d_in[2];
    const float* pt  = (const float*)d_in[3];
    const float* rel = (const float*)d_in[4];
    // d_in[5] reg_basis: circulant structure exploited analytically
    const float* vb1 = (const float*)d_in[6];
    const float* vb2 = (const float*)d_in[7];
    const float* qc  = (const float*)d_in[8];
    const float* kc  = (const float*)d_in[9];
    const float* v0p = (const float*)d_in[10];
    const float* v1p = (const float*)d_in[11];
    const float* v2p = (const float*)d_in[12];
    const float* wm  = (const float*)d_in[13];

    int*   flag = (int*)d_ws;
    float* A4   = (float*)d_ws + 64;
    float* outp = (float*)d_out;

    hipMemsetAsync(d_ws, 0, 256, stream);
    hipLaunchKernelGGL(kprep, dim3(160),  dim3(256), 0, stream,
                       v0p, v1p, v2p, vb1, vb2, A4, msk, flag);
    hipLaunchKernelGGL(kmain, dim3(GRID), dim3(256), 0, stream,
                       x, nbr, msk, pt, rel, qc, kc, A4, wm, flag, outp);
}

// Round 7
// 268.773 us; speedup vs baseline: 4.8079x; 1.0317x over previous
//
#include <hip/hip_runtime.h>

#define NV  20000
#define NNB 12
#define NC  16
#define NH  4
#define VC  4            // vertices concurrent per block
#define GRID (NV/VC)     // 5000

// ---- LDS float offsets (16B-aligned) ----
// F region: F[vn*132+c*8+j] live P1..P6, then HEAD[v*520+hc*8+i] from P7.
#define OFF_QC   0         // [h*132 + c*8 + s]   528
#define OFF_KC   528       //                     528
#define OFF_Q    1056      // [(v*4+h)*8 + i]     128
#define OFF_F    1184      // [vn*132 + c*8 + j] 6336
#define OFF_HEAD 1184      // overlays F after its death (2080)
#define OFF_SC   7520      // [vn*4 + h] scores -> attn in place (192)
#define OFF_DEN  7712      // [v*4 + h]  (16)
#define OFF_NV   7728      // [v]        (8 incl pad)
#define OFF_S4   7736      // [vn*4 + p0..3]  (192)
#define OFF_S2   7928      // [vn*2 + p4..5]  (96)
#define OFF_NB   8024      // int [vn]        (48)
#define OFF_M    8072      // [vn]            (48)
#define SMEM_FL  8120      // 32480 B -> 5 blocks/CU

#define LD8(dst, off) { const float4 _a = *(const float4*)&smem[(off)]; \
                        const float4 _b = *(const float4*)&smem[(off)+4]; \
                        dst[0]=_a.x; dst[1]=_a.y; dst[2]=_a.z; dst[3]=_a.w; \
                        dst[4]=_b.x; dst[5]=_b.y; dst[6]=_b.z; dst[7]=_b.w; }
#define ST8(off, src) { *(float4*)&smem[(off)]   = make_float4(src[0],src[1],src[2],src[3]); \
                        *(float4*)&smem[(off)+4] = make_float4(src[4],src[5],src[6],src[7]); }

// ---------------------------------------------------------------------------
// Merged setup + mask-dtype detect. Blocks 0..95: A4 table; 96..159: detect.
// A4[((p*8 + i)*64 + hc)*8 + j] = A(h,c,i,j,p); hc = h*16+c.
// ---------------------------------------------------------------------------
__global__ __launch_bounds__(256) void kprep(
    const float* __restrict__ v0p, const float* __restrict__ v1p,
    const float* __restrict__ v2p, const float* __restrict__ vb1,
    const float* __restrict__ vb2, float* __restrict__ A4,
    const unsigned char* __restrict__ m, int* __restrict__ flag)
{
    const int b = blockIdx.x, tid = threadIdx.x;
    if (b < 96) {
        int idx = b * 256 + tid;
        int j = idx & 7;
        int t = idx >> 3;
        int hc = t & 63; t >>= 6;
        int i = t & 7;
        int p = t >> 3;
        int h = hc >> 4, c = hc & 15;
        float s = 0.f;
        if (p == 0) {
            s = v0p[h*128 + c*8 + ((j - i + 8) & 7)];
        } else if (p <= 2) {
            int o = p - 1;
            #pragma unroll
            for (int bb = 0; bb < 8; ++bb)
                s += v1p[h*128 + c*8 + bb] * vb1[((bb*2 + o)*8 + i)*8 + j];
        } else {
            int o = p - 3;
            #pragma unroll
            for (int bb = 0; bb < 8; ++bb)
                s += v2p[h*128 + c*8 + bb] * vb2[((bb*3 + o)*8 + i)*8 + j];
        }
        A4[idx] = s;
    } else {
        __shared__ int s_nz;
        if (tid == 0) s_nz = 0;
        __syncthreads();
        int nz = 0;
        for (int k = (b - 96) * 256 + tid; k < NV * NNB; k += 64 * 256) {
            if ((k & 3) != 0 && m[k] != 0) nz = 1;
        }
        if (nz) atomicOr(&s_nz, 1);
        __syncthreads();
        if (tid == 0 && s_nz) atomicOr(flag, 1);   // 1 => byte storage
    }
}

// ---------------------------------------------------------------------------
// Fused main: 4 vertices per block, 8 barriers, 32480 B LDS (5 blocks/CU).
// ---------------------------------------------------------------------------
__global__ __launch_bounds__(256, 4) void kmain(
    const float* __restrict__ x, const int* __restrict__ nbr,
    const unsigned char* __restrict__ mskb, const float* __restrict__ pt,
    const float* __restrict__ rel, const float* __restrict__ qc,
    const float* __restrict__ kc, const float* __restrict__ A4,
    const float* __restrict__ wm, const int* __restrict__ flagp,
    float* __restrict__ out)
{
    const int tid = threadIdx.x;
    const int vbase = blockIdx.x * VC;
    const int bytemode = flagp[0];
    const int* mski = (const int*)mskb;

    __shared__ __align__(16) float smem[SMEM_FL];

    // ---- P0: stage qc/kc, nb, m, scal ----
    for (int k = tid; k < 512; k += 256) {
        smem[OFF_QC + (k>>7)*132 + (k&127)] = qc[k];
        smem[OFF_KC + (k>>7)*132 + (k&127)] = kc[k];
    }
    if (tid < VC*NNB) {
        int gi = vbase*NNB + tid;
        ((int*)smem)[OFF_NB + tid] = nbr[gi];
        int raw = bytemode ? (int)mskb[gi] : mski[gi];
        smem[OFF_M + tid] = raw ? 1.0f : 0.0f;
    }
    if (tid >= 64 && tid < 64 + VC*NNB) {
        int vn = tid - 64;
        float u0 = rel[(vbase*NNB + vn)*2 + 0];
        float u1 = rel[(vbase*NNB + vn)*2 + 1];
        smem[OFF_S4+vn*4+0] = 1.0f;
        smem[OFF_S4+vn*4+1] = u0;
        smem[OFF_S4+vn*4+2] = u1;
        smem[OFF_S4+vn*4+3] = u0*u0;
        smem[OFF_S2+vn*2+0] = 2.0f*u0*u1;
        smem[OFF_S2+vn*2+1] = u1*u1;
    }
    __syncthreads();

    // ---- P1: f[vn][c][i] = m * sum_j pt[vn,i,j] * x[nb][c][j] ----
    // pt read straight from global (12 KB/block slice, L1-resident; 4-way
    // lane broadcast). Frees the old 3264-float staging region.
    if (tid < 192) {
        const int vn = tid >> 2, cq = tid & 3;
        const int nb = ((const int*)smem)[OFF_NB + vn];
        const float m = smem[OFF_M + vn];
        const float4* xg = (const float4*)(x + (size_t)nb*128 + cq*32);
        float xnf[32];
        #pragma unroll
        for (int q = 0; q < 8; ++q) {
            float4 tv = xg[q];
            xnf[q*4+0]=tv.x; xnf[q*4+1]=tv.y; xnf[q*4+2]=tv.z; xnf[q*4+3]=tv.w;
        }
        const float* ptg = pt + (size_t)(vbase*NNB + vn)*64;
        float acc[4][8];
        #pragma unroll
        for (int c4 = 0; c4 < 4; ++c4)
            #pragma unroll
            for (int i = 0; i < 8; ++i) acc[c4][i] = 0.f;
        #pragma unroll
        for (int i = 0; i < 8; ++i) {
            const float4 pA = *(const float4*)(ptg + i*8);
            const float4 pB = *(const float4*)(ptg + i*8 + 4);
            float pj[8] = {pA.x,pA.y,pA.z,pA.w,pB.x,pB.y,pB.z,pB.w};
            #pragma unroll
            for (int c4 = 0; c4 < 4; ++c4)
                #pragma unroll
                for (int j = 0; j < 8; ++j)
                    acc[c4][i] += pj[j] * xnf[c4*8 + j];
        }
        #pragma unroll
        for (int c4 = 0; c4 < 4; ++c4) {
            int c = cq*4 + c4;
            float w[8];
            #pragma unroll
            for (int i = 0; i < 8; ++i) w[i] = m * acc[c4][i];
            ST8(OFF_F + vn*132 + c*8, w);
        }
    }
    __syncthreads();

    // ---- P2: Q (x from global, rotation-in-registers + shuffle reduce) ----
    float K8[8] = {0,0,0,0,0,0,0,0};
    if (tid < 128) {
        const int cs = tid & 7, vh = tid >> 3, v = vh >> 2, h = vh & 3;
        const float* xrow = x + (size_t)(vbase + v)*128;
        float Q8[8] = {0,0,0,0,0,0,0,0};
        #pragma unroll
        for (int t = 0; t < 2; ++t) {
            int c = cs*2 + t;
            const float4 xa = *(const float4*)(xrow + c*8);
            const float4 xb = *(const float4*)(xrow + c*8 + 4);
            float xv[8] = {xa.x,xa.y,xa.z,xa.w,xb.x,xb.y,xb.z,xb.w};
            float qv[8]; LD8(qv, OFF_QC + h*132 + c*8);
            #pragma unroll
            for (int s = 0; s < 8; ++s)
                #pragma unroll
                for (int i = 0; i < 8; ++i)
                    Q8[i] += qv[s] * xv[(i+s)&7];
        }
        #pragma unroll
        for (int msk = 1; msk < 8; msk <<= 1)
            #pragma unroll
            for (int i = 0; i < 8; ++i) Q8[i] += __shfl_xor(Q8[i], msk, 64);
        if (cs == 0) { ST8(OFF_Q + vh*8, Q8); }
    }
    // ---- P3: K (kept in registers) ----
    if (tid < 192) {
        const int vn = tid >> 2, h = tid & 3;
        #pragma unroll 2
        for (int c = 0; c < 16; ++c) {
            float kv[8]; LD8(kv, OFF_KC + h*132 + c*8);
            float fv[8]; LD8(fv, OFF_F + vn*132 + c*8);
            #pragma unroll
            for (int s = 0; s < 8; ++s)
                #pragma unroll
                for (int i = 0; i < 8; ++i)
                    K8[i] += kv[s] * fv[(i+s)&7];
        }
    }
    __syncthreads();

    // ---- P4: scores ----
    if (tid < 192) {
        const int vn = tid >> 2, h = tid & 3, v = vn / 12;
        float q[8]; LD8(q, OFF_Q + (v*4+h)*8);
        float s = 0.f;
        #pragma unroll
        for (int i = 0; i < 8; ++i) s += fmaxf(0.f, q[i] + K8[i]);
        smem[OFF_SC + vn*4 + h] = 0.125f * s * smem[OFF_M + vn];
    }
    __syncthreads();

    // ---- P5a: den, n_valid ----
    if (tid < 16) {
        int v = tid >> 2, h = tid & 3;
        float d = 0.f;
        for (int n = 0; n < 12; ++n) d += smem[OFF_SC + (v*12+n)*4 + h];
        smem[OFF_DEN + tid] = d;
        if (h == 0) {
            float nv = 0.f;
            for (int n = 0; n < 12; ++n) nv += smem[OFF_M + v*12 + n];
            smem[OFF_NV + v] = fmaxf(nv, 1.0f);
        }
    }
    __syncthreads();
    // ---- P5b: attn in-place over SC (own slot; no extra barrier) ----
    if (tid < 192) {
        const int vn = tid >> 2, h = tid & 3, v = vn / 12;
        float den = smem[OFF_DEN + v*4 + h];
        float at = (den < 1e-6f) ? (smem[OFF_M + vn] / smem[OFF_NV + v])
                                 : (smem[OFF_SC + vn*4 + h] / fmaxf(den, 1e-6f));
        smem[OFF_SC + vn*4 + h] = at;
    }
    __syncthreads();

    // ---- P6: G (registers only) + head with A4 from L2 ----
    const int v6 = tid >> 6, h6 = (tid >> 4) & 3, c6 = tid & 15, hc = tid & 63;
    float G[6][8];
    #pragma unroll
    for (int p = 0; p < 6; ++p)
        #pragma unroll
        for (int j = 0; j < 8; ++j) G[p][j] = 0.f;
    for (int n = 0; n < 12; ++n) {
        int vn = v6*12 + n;
        float at = smem[OFF_SC + vn*4 + h6];
        const float4 s4 = *(const float4*)&smem[OFF_S4 + vn*4];
        const float2 s2 = *(const float2*)&smem[OFF_S2 + vn*2];
        float fv[8]; LD8(fv, OFF_F + vn*132 + c6*8);
        float w[6] = {at*s4.x, at*s4.y, at*s4.z, at*s4.w, at*s2.x, at*s2.y};
        #pragma unroll
        for (int p = 0; p < 6; ++p)
            #pragma unroll
            for (int j = 0; j < 8; ++j) G[p][j] += w[p] * fv[j];
    }
    __syncthreads();                  // F dead: HEAD may overwrite its region

    float hd[8] = {0,0,0,0,0,0,0,0};
    #pragma unroll
    for (int p = 0; p < 6; ++p) {
        #pragma unroll
        for (int i = 0; i < 8; ++i) {
            const float4 a0 = *(const float4*)&A4[(((p*8+i)*64 + hc)*8)];
            const float4 a1 = *(const float4*)&A4[(((p*8+i)*64 + hc)*8) + 4];
            hd[i] += a0.x*G[p][0] + a0.y*G[p][1] + a0.z*G[p][2] + a0.w*G[p][3]
                   + a1.x*G[p][4] + a1.y*G[p][5] + a1.z*G[p][6] + a1.w*G[p][7];
        }
    }
    // ---- P7: head -> LDS (overlays dead F region) ----
    ST8(OFF_HEAD + v6*520 + hc*8, hd);
    __syncthreads();

    // ---- P8: projection (rotation-in-registers, wm from L1/L2) ----
    {
        const int v = tid >> 6, o = (tid >> 2) & 15, cs = tid & 3;
        float acc[8] = {0,0,0,0,0,0,0,0};
        #pragma unroll 2
        for (int cc = 0; cc < 16; ++cc) {
            int cp = cc*4 + cs;
            float hh[8]; LD8(hh, OFF_HEAD + v*520 + cp*8);
            const float4 w0 = *(const float4*)&wm[(o*64 + cp)*8];
            const float4 w1 = *(const float4*)&wm[(o*64 + cp)*8 + 4];
            float wv[8] = {w0.x,w0.y,w0.z,w0.w,w1.x,w1.y,w1.z,w1.w};
            #pragma unroll
            for (int d = 0; d < 8; ++d)
                #pragma unroll
                for (int i = 0; i < 8; ++i)
                    acc[i] += wv[d] * hh[(i+d)&7];
        }
        #pragma unroll
        for (int msk = 1; msk < 4; msk <<= 1)
            #pragma unroll
            for (int i = 0; i < 8; ++i) acc[i] += __shfl_xor(acc[i], msk, 64);
        if (cs == 0) {
            float* op = out + (size_t)(vbase + v)*128 + o*8;
            *(float4*)op       = make_float4(acc[0],acc[1],acc[2],acc[3]);
            *(float4*)(op + 4) = make_float4(acc[4],acc[5],acc[6],acc[7]);
        }
    }
}

extern "C" void kernel_launch(void* const* d_in, const int* in_sizes, int n_in,
                              void* d_out, int out_size, void* d_ws, size_t ws_size,
                              hipStream_t stream)
{
    const float* x   = (const float*)d_in[0];
    const int*   nbr = (const int*)d_in[1];
    const unsigned char* msk = (const unsigned char*)d_in[2];
    const float* pt  = (const float*)d_in[3];
    const float* rel = (const float*)d_in[4];
    // d_in[5] reg_basis: circulant structure exploited analytically
    const float* vb1 = (const float*)d_in[6];
    const float* vb2 = (const float*)d_in[7];
    const float* qc  = (const float*)d_in[8];
    const float* kc  = (const float*)d_in[9];
    const float* v0p = (const float*)d_in[10];
    const float* v1p = (const float*)d_in[11];
    const float* v2p = (const float*)d_in[12];
    const float* wm  = (const float*)d_in[13];

    int*   flag = (int*)d_ws;
    float* A4   = (float*)d_ws + 64;
    float* outp = (float*)d_out;

    hipMemsetAsync(d_ws, 0, 256, stream);
    hipLaunchKernelGGL(kprep, dim3(160),  dim3(256), 0, stream,
                       v0p, v1p, v2p, vb1, vb2, A4, msk, flag);
    hipLaunchKernelGGL(kmain, dim3(GRID), dim3(256), 0, stream,
                       x, nbr, msk, pt, rel, qc, kc, A4, wm, flag, outp);
}